// Round 1
// baseline (126.629 us; speedup 1.0000x reference)
//
#include <hip/hip_runtime.h>

#define NT 256

constexpr int L0 = 8192;
constexpr int N1 = 4099;   // (8192+7)>>1
constexpr int N2 = 2053;   // (4099+7)>>1
constexpr int N3 = 1030;   // (2053+7)>>1
constexpr int N4 = 518;    // (1030+7)>>1
constexpr int ROW_OUT = N4 + N4 + N3 + N2 + N1;  // 8218
constexpr int LPAD = 8;

// LDS buffers, sized in 16B slots rounded to multiple of 8 slots (swizzle group)
constexpr int B1_SLOTS = 1032;   // holds cA1 (needs slots <= 1029) / cA3
constexpr int B2_SLOTS = 520;    // holds cA2 (needs slots <= 517)

// lo[i] = sum_j GLO[j] * xsym(2i-6+j)   (GLO = pywt db4 rec_lo = dec_lo reversed)
constexpr float GLO[8] = {
    0.23037781330885523f,  0.7148465705525415f,   0.6308807679295904f,
   -0.02798376941698385f, -0.18703481171888114f,  0.030841381835986965f,
    0.032883011666982945f, -0.010597401784997278f };
// hi[i] = sum_j GHI[j] * xsym(2i-6+j)
constexpr float GHI[8] = {
   -0.010597401784997278f, -0.032883011666982945f, 0.030841381835986965f,
    0.18703481171888114f,  -0.02798376941698385f,  -0.6308807679295904f,
    0.7148465705525415f,   -0.23037781330885523f };

// XOR swizzle at 16B-slot granularity: bijective involution within each 8-slot
// group. Makes lane-stride-2-slot b128 reads and lane-stride-1-slot writes
// both bank-conflict-free.
__device__ __forceinline__ int swz_slot(int s) { return s ^ ((s >> 3) & 7); }
__device__ __forceinline__ int swzf(int f) { return (swz_slot(f >> 2) << 2) | (f & 3); }

// w[16] = xsym window starting at q = 8t-8 (buffer f = 8t). Outputs i = 4t+m
// use taps w[2m+2 .. 2m+9]. Same fmaf order as verified kernel -> bit-exact.
__device__ __forceinline__ void conv4(const float* __restrict__ w,
                                      float* __restrict__ lo,
                                      float* __restrict__ hi)
{
#pragma unroll
    for (int m = 0; m < 4; ++m) {
        float l = 0.f, h = 0.f;
#pragma unroll
        for (int j = 0; j < 8; ++j) {
            float v = w[2 * m + 2 + j];
            l = fmaf(GLO[j], v, l);
            h = fmaf(GHI[j], v, h);
        }
        lo[m] = l;
        hi[m] = h;
    }
}

// Store 4 lo outputs of task t into swizzled LDS buffer, with fused symmetric
// pads (front pad f=LPAD-1-i holds output i; tail pad holds output 2*nout-1-i
// at f=LPAD+2*nout-1-i). Partial tasks take the guarded scalar path so no
// garbage is ever written into the pad region (avoids a cross-thread race
// with the pad writers).
__device__ __forceinline__ void store_lo_lds(float* __restrict__ bout, int nout,
                                             int t, const float* __restrict__ lo)
{
    const int i0 = 4 * t;
    if (i0 + 4 <= nout) {
        // f = LPAD + i0 = 8 + 4t -> slot t+2, offset 0 (16B aligned)
        *(float4*)(bout + 4 * swz_slot(t + 2)) = make_float4(lo[0], lo[1], lo[2], lo[3]);
    } else {
#pragma unroll
        for (int m = 0; m < 4; ++m)
            if (i0 + m < nout) bout[swzf(LPAD + i0 + m)] = lo[m];
    }
    if (t < 2) {  // outputs 0..7 -> front pads (i < 7)
#pragma unroll
        for (int m = 0; m < 4; ++m) {
            int i = i0 + m;
            if (i < 7) bout[swzf(LPAD - 1 - i)] = lo[m];
        }
    }
    if (i0 + 3 >= nout - 7) {  // last 7 outputs -> tail pads
#pragma unroll
        for (int m = 0; m < 4; ++m) {
            int i = i0 + m;
            if (i < nout && i >= nout - 7) bout[swzf(LPAD + 2 * nout - 1 - i)] = lo[m];
        }
    }
}

// Level 1: straight from global memory (no LDS staging). Each task t computes
// outputs 4t..4t+3 from the 16-float aligned window x[8t-8 .. 8t+7]; only the
// two edge tasks take the symmetric-gather slow path. lo -> swizzled LDS B1,
// hi -> cD1 in global out.
__device__ __forceinline__ void level1(const float* __restrict__ xr,
                                       float* __restrict__ bout,
                                       float* __restrict__ hi_g, int tid)
{
    constexpr int ntask = (N1 + 3) >> 2;  // 1025
    for (int t = tid; t < ntask; t += NT) {
        float w[16];
        if (t >= 1 && t < (L0 / 8)) {
            const float4* p = (const float4*)(xr + 8 * t - 8);
            float4 r0 = p[0], r1 = p[1], r2 = p[2], r3 = p[3];
            w[0] = r0.x;  w[1] = r0.y;  w[2] = r0.z;  w[3] = r0.w;
            w[4] = r1.x;  w[5] = r1.y;  w[6] = r1.z;  w[7] = r1.w;
            w[8] = r2.x;  w[9] = r2.y;  w[10] = r2.z; w[11] = r2.w;
            w[12] = r3.x; w[13] = r3.y; w[14] = r3.z; w[15] = r3.w;
        } else {
#pragma unroll
            for (int j = 0; j < 16; ++j) {
                int q = 8 * t - 8 + j;
                q = (q < 0) ? (-1 - q) : q;
                q = (q >= L0) ? (2 * L0 - 1 - q) : q;
                w[j] = xr[q];
            }
        }
        float lo[4], hi[4];
        conv4(w, lo, hi);
        store_lo_lds(bout, N1, t, lo);
        const int i0 = 4 * t;
#pragma unroll
        for (int m = 0; m < 4; ++m)
            if (i0 + m < N1) hi_g[i0 + m] = hi[m];
    }
}

// Levels 2-4: input from swizzled LDS. 4 outputs/task via 4x ds_read_b128
// (slots 2t..2t+3, swizzled -> conflict-free). LAST sends lo to global.
template<bool LAST>
__device__ __forceinline__ void level_lds(const float* __restrict__ bin, int nout,
                                          float* __restrict__ bout,
                                          float* __restrict__ lo_g,
                                          float* __restrict__ hi_g, int tid)
{
    const int ntask = (nout + 3) >> 2;
    for (int t = tid; t < ntask; t += NT) {
        float4 r0 = *(const float4*)(bin + 4 * swz_slot(2 * t + 0));
        float4 r1 = *(const float4*)(bin + 4 * swz_slot(2 * t + 1));
        float4 r2 = *(const float4*)(bin + 4 * swz_slot(2 * t + 2));
        float4 r3 = *(const float4*)(bin + 4 * swz_slot(2 * t + 3));
        float w[16] = { r0.x, r0.y, r0.z, r0.w, r1.x, r1.y, r1.z, r1.w,
                        r2.x, r2.y, r2.z, r2.w, r3.x, r3.y, r3.z, r3.w };
        float lo[4], hi[4];
        conv4(w, lo, hi);
        const int i0 = 4 * t;
        if (LAST) {
#pragma unroll
            for (int m = 0; m < 4; ++m)
                if (i0 + m < nout) lo_g[i0 + m] = lo[m];
        } else {
            store_lo_lds(bout, nout, t, lo);
        }
#pragma unroll
        for (int m = 0; m < 4; ++m)
            if (i0 + m < nout) hi_g[i0 + m] = hi[m];
    }
}

__global__ __launch_bounds__(NT) void wavedec4_db4(const float* __restrict__ x,
                                                   float* __restrict__ out)
{
    // 24.8 KiB total -> 6 blocks/CU (was 48 KiB -> 3 blocks/CU)
    __shared__ float B1[B1_SLOTS * 4];
    __shared__ float B2[B2_SLOTS * 4];
    const int tid = threadIdx.x;
    const size_t row = blockIdx.x;
    const float* __restrict__ xr = x + row * (size_t)L0;
    float* __restrict__ outr = out + row * (size_t)ROW_OUT;

    // L1: global -> cA1 in B1 (+pads fused), cD1 -> out[4119..]
    level1(xr, B1, outr + (N4 + N4 + N3 + N2), tid);
    __syncthreads();
    // L2: B1(4099) -> cA2 in B2 (+pads), cD2 -> out[2066..]
    level_lds<false>(B1, N2, B2, nullptr, outr + (N4 + N4 + N3), tid);
    __syncthreads();
    // L3: B2(2053) -> cA3 in B1 (+pads), cD3 -> out[1036..]
    level_lds<false>(B2, N3, B1, nullptr, outr + (N4 + N4), tid);
    __syncthreads();
    // L4: B1(1030) -> cA4 -> out[0..518), cD4 -> out[518..1036)
    level_lds<true>(B1, N4, nullptr, outr, outr + N4, tid);
}

extern "C" void kernel_launch(void* const* d_in, const int* in_sizes, int n_in,
                              void* d_out, int out_size, void* d_ws, size_t ws_size,
                              hipStream_t stream) {
    const float* x = (const float*)d_in[0];
    float* out = (float*)d_out;
    const int rows = in_sizes[0] / L0;  // 64*32 = 2048
    wavedec4_db4<<<dim3(rows), dim3(NT), 0, stream>>>(x, out);
}

// Round 2
// 126.438 us; speedup vs baseline: 1.0015x; 1.0015x over previous
//
#include <hip/hip_runtime.h>

#define NT 256

constexpr int L0 = 8192;
constexpr int N1 = 4099;   // (8192+7)>>1
constexpr int N2 = 2053;   // (4099+7)>>1
constexpr int N3 = 1030;   // (2053+7)>>1
constexpr int N4 = 518;    // (1030+7)>>1
constexpr int ROW_OUT = N4 + N4 + N3 + N2 + N1;  // 8218
constexpr int LPAD = 8;

// Single LDS buffer in 16B slots (multiple of 8 slots = one swizzle group).
// Holds level input [LPAD + n + 7] floats; max is cA1: 8+4099+7=4114 -> 1029
// slots -> round to 1032. 16512 B/block -> 8 blocks/CU (was 24.5K -> 6).
constexpr int B1_SLOTS = 1032;

// lo[i] = sum_j GLO[j] * xsym(2i-6+j)   (GLO = pywt db4 rec_lo = dec_lo reversed)
constexpr float GLO[8] = {
    0.23037781330885523f,  0.7148465705525415f,   0.6308807679295904f,
   -0.02798376941698385f, -0.18703481171888114f,  0.030841381835986965f,
    0.032883011666982945f, -0.010597401784997278f };
// hi[i] = sum_j GHI[j] * xsym(2i-6+j)
constexpr float GHI[8] = {
   -0.010597401784997278f, -0.032883011666982945f, 0.030841381835986965f,
    0.18703481171888114f,  -0.02798376941698385f,  -0.6308807679295904f,
    0.7148465705525415f,   -0.23037781330885523f };

// XOR swizzle at 16B-slot granularity: bijective involution within each 8-slot
// group. Lane-stride-1-slot writes and lane-stride-2-slot b128 reads both
// become bank-conflict-free.
__device__ __forceinline__ int swz_slot(int s) { return s ^ ((s >> 3) & 7); }
__device__ __forceinline__ int swzf(int f) { return (swz_slot(f >> 2) << 2) | (f & 3); }

// w[16] = xsym window starting at q = 8t-8 (buffer f = 8t). Outputs i = 4t+m
// use taps w[2m+2 .. 2m+9]. Same fmaf order as verified kernel -> bit-exact.
__device__ __forceinline__ void conv4(const float* __restrict__ w,
                                      float* __restrict__ lo,
                                      float* __restrict__ hi)
{
#pragma unroll
    for (int m = 0; m < 4; ++m) {
        float l = 0.f, h = 0.f;
#pragma unroll
        for (int j = 0; j < 8; ++j) {
            float v = w[2 * m + 2 + j];
            l = fmaf(GLO[j], v, l);
            h = fmaf(GHI[j], v, h);
        }
        lo[m] = l;
        hi[m] = h;
    }
}

// Store 4 lo outputs of task t into swizzled LDS buffer front, with fused
// symmetric pads. Partial tasks take the guarded scalar path so no garbage is
// ever written into the pad region.
__device__ __forceinline__ void store_lo_lds(float* __restrict__ bout, int nout,
                                             int t, const float* __restrict__ lo)
{
    const int i0 = 4 * t;
    if (i0 + 4 <= nout) {
        // f = LPAD + i0 = 8 + 4t -> slot t+2, offset 0 (16B aligned)
        *(float4*)(bout + 4 * swz_slot(t + 2)) = make_float4(lo[0], lo[1], lo[2], lo[3]);
    } else {
#pragma unroll
        for (int m = 0; m < 4; ++m)
            if (i0 + m < nout) bout[swzf(LPAD + i0 + m)] = lo[m];
    }
    if (t < 2) {  // outputs 0..7 -> front pads (i < 7)
#pragma unroll
        for (int m = 0; m < 4; ++m) {
            int i = i0 + m;
            if (i < 7) bout[swzf(LPAD - 1 - i)] = lo[m];
        }
    }
    if (i0 + 3 >= nout - 7) {  // last 7 outputs -> tail pads at f=LPAD+nout+t
#pragma unroll
        for (int m = 0; m < 4; ++m) {
            int i = i0 + m;
            if (i < nout && i >= nout - 7) bout[swzf(LPAD + 2 * nout - 1 - i)] = lo[m];
        }
    }
}

// Level 1: straight from global memory. Task t computes outputs 4t..4t+3 from
// the 16-float aligned window x[8t-8 .. 8t+7]; edge tasks take the symmetric-
// gather slow path. lo -> swizzled LDS B1, hi -> cD1 global.
__device__ __forceinline__ void level1(const float* __restrict__ xr,
                                       float* __restrict__ bout,
                                       float* __restrict__ hi_g, int tid)
{
    constexpr int ntask = (N1 + 3) >> 2;  // 1025
    for (int t = tid; t < ntask; t += NT) {
        float w[16];
        if (t >= 1 && t < (L0 / 8)) {
            const float4* p = (const float4*)(xr + 8 * t - 8);
            float4 r0 = p[0], r1 = p[1], r2 = p[2], r3 = p[3];
            w[0] = r0.x;  w[1] = r0.y;  w[2] = r0.z;  w[3] = r0.w;
            w[4] = r1.x;  w[5] = r1.y;  w[6] = r1.z;  w[7] = r1.w;
            w[8] = r2.x;  w[9] = r2.y;  w[10] = r2.z; w[11] = r2.w;
            w[12] = r3.x; w[13] = r3.y; w[14] = r3.z; w[15] = r3.w;
        } else {
#pragma unroll
            for (int j = 0; j < 16; ++j) {
                int q = 8 * t - 8 + j;
                q = (q < 0) ? (-1 - q) : q;
                q = (q >= L0) ? (2 * L0 - 1 - q) : q;
                w[j] = xr[q];
            }
        }
        float lo[4], hi[4];
        conv4(w, lo, hi);
        store_lo_lds(bout, N1, t, lo);
        const int i0 = 4 * t;
#pragma unroll
        for (int m = 0; m < 4; ++m)
            if (i0 + m < N1) hi_g[i0 + m] = hi[m];
    }
}

// Mid levels (L2, L3): read input from B1, hold lo in registers, barrier,
// write lo back to B1 FRONT (parent data is dead after the barrier). This
// in-place reuse keeps total LDS at one buffer. hi -> global.
// Reads past the valid region only ever feed outputs >= NOUT (guarded).
template<int NOUT>
__device__ __forceinline__ void level_mid(float* __restrict__ B1,
                                          float* __restrict__ hi_g, int tid)
{
    constexpr int ntask = (NOUT + 3) >> 2;
    constexpr int KMAX = (ntask + NT - 1) / NT;
    float lo_h[KMAX][4];
#pragma unroll
    for (int k = 0; k < KMAX; ++k) {
        const int t = tid + k * NT;
        if (t < ntask) {
            float4 r0 = *(const float4*)(B1 + 4 * swz_slot(2 * t + 0));
            float4 r1 = *(const float4*)(B1 + 4 * swz_slot(2 * t + 1));
            float4 r2 = *(const float4*)(B1 + 4 * swz_slot(2 * t + 2));
            float4 r3 = *(const float4*)(B1 + 4 * swz_slot(2 * t + 3));
            float w[16] = { r0.x, r0.y, r0.z, r0.w, r1.x, r1.y, r1.z, r1.w,
                            r2.x, r2.y, r2.z, r2.w, r3.x, r3.y, r3.z, r3.w };
            float hi[4];
            conv4(w, lo_h[k], hi);
            const int i0 = 4 * t;
#pragma unroll
            for (int m = 0; m < 4; ++m)
                if (i0 + m < NOUT) hi_g[i0 + m] = hi[m];
        }
    }
    __syncthreads();   // all reads of parent level done -> front is writable
#pragma unroll
    for (int k = 0; k < KMAX; ++k) {
        const int t = tid + k * NT;
        if (t < ntask) store_lo_lds(B1, NOUT, t, lo_h[k]);
    }
    __syncthreads();
}

// Last level (L4): read B1, both outputs straight to global.
__device__ __forceinline__ void level_last(const float* __restrict__ B1,
                                           float* __restrict__ lo_g,
                                           float* __restrict__ hi_g, int tid)
{
    constexpr int ntask = (N4 + 3) >> 2;  // 130
    for (int t = tid; t < ntask; t += NT) {
        float4 r0 = *(const float4*)(B1 + 4 * swz_slot(2 * t + 0));
        float4 r1 = *(const float4*)(B1 + 4 * swz_slot(2 * t + 1));
        float4 r2 = *(const float4*)(B1 + 4 * swz_slot(2 * t + 2));
        float4 r3 = *(const float4*)(B1 + 4 * swz_slot(2 * t + 3));
        float w[16] = { r0.x, r0.y, r0.z, r0.w, r1.x, r1.y, r1.z, r1.w,
                        r2.x, r2.y, r2.z, r2.w, r3.x, r3.y, r3.z, r3.w };
        float lo[4], hi[4];
        conv4(w, lo, hi);
        const int i0 = 4 * t;
#pragma unroll
        for (int m = 0; m < 4; ++m) {
            if (i0 + m < N4) {
                lo_g[i0 + m] = lo[m];
                hi_g[i0 + m] = hi[m];
            }
        }
    }
}

__global__ __launch_bounds__(NT) void wavedec4_db4(const float* __restrict__ x,
                                                   float* __restrict__ out)
{
    // 16.5 KiB -> 8 blocks/CU; 8 blocks x 4 waves = 32 waves/CU (the cap),
    // 2048 threads/CU (the cap) -> entire 2048-block grid co-resident, no tail.
    __shared__ float4 B1v[B1_SLOTS];
    float* B1 = (float*)B1v;
    const int tid = threadIdx.x;
    const size_t row = blockIdx.x;
    const float* __restrict__ xr = x + row * (size_t)L0;
    float* __restrict__ outr = out + row * (size_t)ROW_OUT;

    // L1: global -> cA1 in B1 (+pads fused), cD1 -> out[4119..]
    level1(xr, B1, outr + (N4 + N4 + N3 + N2), tid);
    __syncthreads();
    // L2: B1(cA1,4099) -> cA2 back into B1 front (+pads), cD2 -> out[2066..]
    level_mid<N2>(B1, outr + (N4 + N4 + N3), tid);
    // L3: B1(cA2,2053) -> cA3 back into B1 front (+pads), cD3 -> out[1036..]
    level_mid<N3>(B1, outr + (N4 + N4), tid);
    // L4: B1(cA3,1030) -> cA4 -> out[0..518), cD4 -> out[518..1036)
    level_last(B1, outr, outr + N4, tid);
}

extern "C" void kernel_launch(void* const* d_in, const int* in_sizes, int n_in,
                              void* d_out, int out_size, void* d_ws, size_t ws_size,
                              hipStream_t stream) {
    const float* x = (const float*)d_in[0];
    float* out = (float*)d_out;
    const int rows = in_sizes[0] / L0;  // 64*32 = 2048
    wavedec4_db4<<<dim3(rows), dim3(NT), 0, stream>>>(x, out);
}

// Round 3
// 116.446 us; speedup vs baseline: 1.0874x; 1.0858x over previous
//
#include <hip/hip_runtime.h>

#define NT 512

constexpr int L0 = 8192;
constexpr int N1 = 4099;   // (8192+7)>>1
constexpr int N2 = 2053;   // (4099+7)>>1
constexpr int N3 = 1030;   // (2053+7)>>1
constexpr int N4 = 518;    // (1030+7)>>1
constexpr int ROW_OUT = N4 + N4 + N3 + N2 + N1;  // 8218
constexpr int OFF_A4 = 0;
constexpr int OFF_D4 = 518;
constexpr int OFF_D3 = 1036;
constexpr int OFF_D2 = 2066;
constexpr int OFF_D1 = 4119;

// Halo SoA stride (slots per coefficient lane). Needs NT + tail slots:
// cA1 view [8][513], cA2 view [4][514], cA3 view [2][515]. 520 covers all.
constexpr int HS = 520;

// lo[i] = sum_j GLO[j] * xsym(2i-6+j)   (GLO = pywt db4 rec_lo = dec_lo reversed)
constexpr float GLO[8] = {
    0.23037781330885523f,  0.7148465705525415f,   0.6308807679295904f,
   -0.02798376941698385f, -0.18703481171888114f,  0.030841381835986965f,
    0.032883011666982945f, -0.010597401784997278f };
// hi[i] = sum_j GHI[j] * xsym(2i-6+j)
constexpr float GHI[8] = {
   -0.010597401784997278f, -0.032883011666982945f, 0.030841381835986965f,
    0.18703481171888114f,  -0.02798376941698385f,  -0.6308807679295904f,
    0.7148465705525415f,   -0.23037781330885523f };

// Register-resident cascade:
//  - each thread owns 16 input floats (+8 halo) in registers, computes 8 L1
//    outputs, keeps cA1 in regs; publishes lo to LDS SoA halo (lane-stride-1,
//    conflict-free); each next level reads only 6 halo floats from LDS.
//  - hA (cA1 / cA3 views) and hB (cA2 view) ping-pong -> 3 barriers total.
//  - ragged tails (3/5/6/6 outputs) computed by designated threads from the
//    published LDS values with symmetric reflection.
__global__ __launch_bounds__(NT, 8) void wavedec4_db4(const float* __restrict__ x,
                                                      float* __restrict__ out)
{
    __shared__ float hA[8 * HS];   // 16640 B : cA1 [m=g&7][g>>3], later cA3 [g&1][g>>1]
    __shared__ float hB[4 * HS];   //  8320 B : cA2 [g&3][g>>2]
    const int t = threadIdx.x;
    const float* __restrict__ xr = x + blockIdx.x * (size_t)L0;
    float* __restrict__ outr = out + blockIdx.x * (size_t)ROW_OUT;

    // ---- load x window [16t-8, 16t+16) into registers, all loads up front ----
    float xw[24];
    if (t > 0) {
        const float4* p = (const float4*)(xr + 16 * t - 8);
        float4 v0 = p[0], v1 = p[1], v2 = p[2], v3 = p[3], v4 = p[4], v5 = p[5];
        xw[0] = v0.x;  xw[1] = v0.y;  xw[2] = v0.z;  xw[3] = v0.w;
        xw[4] = v1.x;  xw[5] = v1.y;  xw[6] = v1.z;  xw[7] = v1.w;
        xw[8] = v2.x;  xw[9] = v2.y;  xw[10] = v2.z; xw[11] = v2.w;
        xw[12] = v3.x; xw[13] = v3.y; xw[14] = v3.z; xw[15] = v3.w;
        xw[16] = v4.x; xw[17] = v4.y; xw[18] = v4.z; xw[19] = v4.w;
        xw[20] = v5.x; xw[21] = v5.y; xw[22] = v5.z; xw[23] = v5.w;
    } else {
        const float4* p = (const float4*)xr;
        float4 v0 = p[0], v1 = p[1], v2 = p[2], v3 = p[3];
        xw[8] = v0.x;  xw[9] = v0.y;  xw[10] = v0.z; xw[11] = v0.w;
        xw[12] = v1.x; xw[13] = v1.y; xw[14] = v1.z; xw[15] = v1.w;
        xw[16] = v2.x; xw[17] = v2.y; xw[18] = v2.z; xw[19] = v2.w;
        xw[20] = v3.x; xw[21] = v3.y; xw[22] = v3.z; xw[23] = v3.w;
#pragma unroll
        for (int k = 0; k < 8; ++k) xw[k] = xw[15 - k];   // xsym(k-8) = x[7-k]
    }

    // ---- L1: outputs i = 8t+m, taps xw[2m+2+j] ----
    float lo1[8];
#pragma unroll
    for (int m = 0; m < 8; ++m) {
        float l = 0.f, h = 0.f;
#pragma unroll
        for (int j = 0; j < 8; ++j) {
            float v = xw[2 * m + 2 + j];
            l = fmaf(GLO[j], v, l);
            h = fmaf(GHI[j], v, h);
        }
        lo1[m] = l;
        outr[OFF_D1 + 8 * t + m] = h;
        hA[m * HS + t] = l;
    }
    if (t == 8) {   // L1 tail: i = 4096..4098 from x[8186..8191] (+reflection)
        float xt[6];
#pragma unroll
        for (int k = 0; k < 6; ++k) xt[k] = xr[8186 + k];
#pragma unroll
        for (int e = 0; e < 3; ++e) {
            const int i = 4096 + e;
            float l = 0.f, h = 0.f;
#pragma unroll
            for (int j = 0; j < 8; ++j) {
                int q = 2 * i - 6 + j;
                int idx = ((q <= 8191) ? q : (16383 - q)) - 8186;
                float v = xt[idx];
                l = fmaf(GLO[j], v, l);
                h = fmaf(GHI[j], v, h);
            }
            outr[OFF_D1 + i] = h;
            hA[(i & 7) * HS + (i >> 3)] = l;
        }
    }
    __syncthreads();

    // ---- L2: outputs j = 4t+m, taps w2[2m+j'] where w2[k] = cA1[8t-6+k] ----
    float w2[14];
#pragma unroll
    for (int k = 0; k < 6; ++k) {
        int g = 8 * t - 6 + k;
        if (g < 0) g = -1 - g;                 // front reflection (t=0 only)
        w2[k] = hA[(g & 7) * HS + (g >> 3)];
    }
#pragma unroll
    for (int m = 0; m < 8; ++m) w2[6 + m] = lo1[m];
    float lo2[4];
#pragma unroll
    for (int m = 0; m < 4; ++m) {
        float l = 0.f, h = 0.f;
#pragma unroll
        for (int j = 0; j < 8; ++j) {
            float v = w2[2 * m + j];
            l = fmaf(GLO[j], v, l);
            h = fmaf(GHI[j], v, h);
        }
        lo2[m] = l;
        outr[OFF_D2 + 4 * t + m] = h;
        hB[m * HS + t] = l;
    }
    if (t < 5) {    // L2 tail: j = 2048..2052 from published cA1 (+tail reflection)
        const int jj = 2048 + t;
        float l = 0.f, h = 0.f;
#pragma unroll
        for (int j = 0; j < 8; ++j) {
            int g = 2 * jj - 6 + j;
            if (g > 4098) g = 8197 - g;        // reflect at N1
            float v = hA[(g & 7) * HS + (g >> 3)];
            l = fmaf(GLO[j], v, l);
            h = fmaf(GHI[j], v, h);
        }
        outr[OFF_D2 + jj] = h;
        hB[(jj & 3) * HS + (jj >> 2)] = l;
    }
    __syncthreads();

    // ---- L3: outputs j = 2t+m, taps w3[2m+j'] where w3[k] = cA2[4t-6+k] ----
    float w3[10];
#pragma unroll
    for (int k = 0; k < 6; ++k) {
        int g = 4 * t - 6 + k;
        if (g < 0) g = -1 - g;
        w3[k] = hB[(g & 3) * HS + (g >> 2)];
    }
#pragma unroll
    for (int m = 0; m < 4; ++m) w3[6 + m] = lo2[m];
    float lo3[2];
#pragma unroll
    for (int m = 0; m < 2; ++m) {
        float l = 0.f, h = 0.f;
#pragma unroll
        for (int j = 0; j < 8; ++j) {
            float v = w3[2 * m + j];
            l = fmaf(GLO[j], v, l);
            h = fmaf(GHI[j], v, h);
        }
        lo3[m] = l;
        outr[OFF_D3 + 2 * t + m] = h;
        hA[m * HS + t] = l;                    // cA3 pair view: (2t+m)&1=m, >>1=t
    }
    if (t < 6) {    // L3 tail: j = 1024..1029 from published cA2 (+reflection)
        const int jj = 1024 + t;
        float l = 0.f, h = 0.f;
#pragma unroll
        for (int j = 0; j < 8; ++j) {
            int g = 2 * jj - 6 + j;
            if (g > 2052) g = 4105 - g;        // reflect at N2
            float v = hB[(g & 3) * HS + (g >> 2)];
            l = fmaf(GLO[j], v, l);
            h = fmaf(GHI[j], v, h);
        }
        outr[OFF_D3 + jj] = h;
        const int gg = jj;                     // cA3 index
        hA[(gg & 1) * HS + (gg >> 1)] = l;
    }
    __syncthreads();

    // ---- L4: output j = t, taps w4[j'] where w4[k] = cA3[2t-6+k] ----
    float w4[8];
#pragma unroll
    for (int k = 0; k < 6; ++k) {
        int g = 2 * t - 6 + k;
        if (g < 0) g = -1 - g;
        w4[k] = hA[(g & 1) * HS + (g >> 1)];
    }
    w4[6] = lo3[0];
    w4[7] = lo3[1];
    {
        float l = 0.f, h = 0.f;
#pragma unroll
        for (int j = 0; j < 8; ++j) {
            float v = w4[j];
            l = fmaf(GLO[j], v, l);
            h = fmaf(GHI[j], v, h);
        }
        outr[OFF_A4 + t] = l;
        outr[OFF_D4 + t] = h;
    }
    if (t < 6) {    // L4 tail: j = 512..517 from published cA3 (+reflection)
        const int jj = 512 + t;
        float l = 0.f, h = 0.f;
#pragma unroll
        for (int j = 0; j < 8; ++j) {
            int g = 2 * jj - 6 + j;
            if (g > 1029) g = 2059 - g;        // reflect at N3
            float v = hA[(g & 1) * HS + (g >> 1)];
            l = fmaf(GLO[j], v, l);
            h = fmaf(GHI[j], v, h);
        }
        outr[OFF_A4 + jj] = l;
        outr[OFF_D4 + jj] = h;
    }
}

extern "C" void kernel_launch(void* const* d_in, const int* in_sizes, int n_in,
                              void* d_out, int out_size, void* d_ws, size_t ws_size,
                              hipStream_t stream) {
    const float* x = (const float*)d_in[0];
    float* out = (float*)d_out;
    const int rows = in_sizes[0] / L0;  // 64*32 = 2048
    wavedec4_db4<<<dim3(rows), dim3(NT), 0, stream>>>(x, out);
}